// Round 9
// baseline (747.517 us; speedup 1.0000x reference)
//
#include <hip/hip_runtime.h>

#define N_NODES     8192
#define N_FEAT      1024
#define N_FILT      4
#define MAXDEG      8
#define BLK         256                 // steps per speculation block
#define NB          (N_NODES / BLK)     // 32

// ---------------------------------------------------------------------------
// Kernel A: filtT[f][v] = (relu(X @ W1^T + b1) @ W2^T + b2)[v][f]
// ---------------------------------------------------------------------------
__global__ __launch_bounds__(256) void filt_kernel(
    const float* __restrict__ X, const float* __restrict__ W1,
    const float* __restrict__ b1, const float* __restrict__ W2,
    const float* __restrict__ b2, float* __restrict__ filtT)
{
    const int node = blockIdx.x * 8 + (threadIdx.x >> 5);
    const int h    = threadIdx.x & 31;
    const float* xr = X  + (size_t)node * N_FEAT;
    const float* wr = W1 + (size_t)h    * N_FEAT;
    float acc = 0.f;
    for (int j = 0; j < N_FEAT; j += 4) {
        float4 xv = *reinterpret_cast<const float4*>(xr + j);
        float4 wv = *reinterpret_cast<const float4*>(wr + j);
        acc += xv.x * wv.x + xv.y * wv.y + xv.z * wv.z + xv.w * wv.w;
    }
    float hv = fmaxf(acc + b1[h], 0.f);
    #pragma unroll
    for (int fo = 0; fo < N_FILT; ++fo) {
        float v = hv * W2[fo * 32 + h];
        for (int off = 16; off; off >>= 1) v += __shfl_xor(v, off, 32);
        if (h == 0) filtT[fo * N_NODES + node] = v + b2[fo];
    }
}

// ---------------------------------------------------------------------------
// Kernel R1: partial stable-rank. 512 blocks: f(2b) x scan-chunk cs(2b) x
// vertex-chunk cv(5b).
// ---------------------------------------------------------------------------
__global__ __launch_bounds__(256) void rank_partial_kernel(
    const float* __restrict__ filtT, unsigned short* __restrict__ partial)
{
    const int b  = blockIdx.x;
    const int f  = b >> 7;
    const int cs = (b >> 5) & 3;
    const int cv = b & 31;
    const int v  = (cv << 8) + threadIdx.x;
    const float myv = filtT[(f << 13) + v];

    __shared__ float4 tile[512];
    const float4* src = reinterpret_cast<const float4*>(filtT + (f << 13) + cs * 2048);
    for (int i = threadIdx.x; i < 512; i += 256) tile[i] = src[i];
    __syncthreads();

    int cnt = 0;
    const int ubase = cs * 2048;
    #pragma unroll 4
    for (int j = 0; j < 512; ++j) {
        float4 wv = tile[j];
        int u = ubase + j * 4;
        cnt += (wv.x < myv) || (wv.x == myv && (u + 0) < v);
        cnt += (wv.y < myv) || (wv.y == myv && (u + 1) < v);
        cnt += (wv.z < myv) || (wv.z == myv && (u + 2) < v);
        cnt += (wv.w < myv) || (wv.w == myv && (u + 3) < v);
    }
    partial[((f * 4 + cs) << 13) + v] = (unsigned short)cnt;
}

// ---------------------------------------------------------------------------
// Kernel R2: pos = sum of 4 partials; order[pos] = v.
// ---------------------------------------------------------------------------
__global__ __launch_bounds__(256) void rank_final_kernel(
    const unsigned short* __restrict__ partial,
    unsigned short* __restrict__ pos16, unsigned short* __restrict__ order16)
{
    int g = blockIdx.x * 256 + threadIdx.x;   // 0 .. 32767
    int f = g >> 13, v = g & 8191;
    int r = (int)partial[((f * 4 + 0) << 13) + v]
          + (int)partial[((f * 4 + 1) << 13) + v]
          + (int)partial[((f * 4 + 2) << 13) + v]
          + (int)partial[((f * 4 + 3) << 13) + v];
    pos16[(f << 13) + v] = (unsigned short)r;
    order16[(f << 13) + r] = (unsigned short)v;
}

// ---------------------------------------------------------------------------
// Kernel E: static edge filter.  et[f][s*8+k] = min(pos[dst[order[s]*8+k]], s)
// ---------------------------------------------------------------------------
__global__ __launch_bounds__(256) void etable_kernel(
    const unsigned short* __restrict__ order16,
    const unsigned short* __restrict__ pos16,
    const int* __restrict__ edge_dst,
    unsigned short* __restrict__ et)
{
    const int f  = blockIdx.x >> 5;
    const int e0 = ((blockIdx.x & 31) << 11);
    for (int i = threadIdx.x; i < 2048; i += 256) {
        int e = e0 + i;
        int s = e >> 3, k = e & 7;
        int v = (int)order16[(f << 13) + s];
        int u = edge_dst[v * MAXDEG + k];
        int q = (int)pos16[(f << 13) + u];
        et[(size_t)f * (N_NODES * MAXDEG) + e] = (unsigned short)(q < s ? q : s);
    }
}

// ---------------------------------------------------------------------------
// Kernel B: PIPELINED block-speculative union-find.
// pd[v] = par | (dth<<16); parents strictly decrease (point to older pos).
// Pipeline: waves 1-3 classify block it (pass1 chase + pure-attach +
// opportunistic pass2 re-chase, NO mid-barrier) into double-buffered
// per-wave ordered sublists, while wave 0 exactly replays block it-1's
// impure list. One __syncthreads per iteration.
//
// Soundness:
//  - every pd write stores an ANCESTOR of the written vertex; chases are
//    monotone decreasing -> terminate; any interleaved read is old-or-new
//    on an aligned dword -> chases land on valid ancestors.
//  - pure attach requires all edges to chase to ONE vertex r: their true
//    components at step s all contain r -> one component -> pure; attaching
//    par[s]=r is valid even if r is no longer a root (ancestor suffices),
//    and death[s]=s regardless.
//  - staleness can only create FALSE impures; wave-0 replay (ascending s,
//    after barrier, all merges < s applied) resolves them exactly.
//  - replay of block b-1 touches only positions < lo_b; classify of block b
//    writes only positions >= lo_b: no write-write races.
// ---------------------------------------------------------------------------
__device__ __forceinline__ int row8min(int v) {
    int t = min(v, __builtin_amdgcn_mov_dpp(v, 0xB1, 0xF, 0xF, true));   // quad xor1
    t = min(t, __builtin_amdgcn_mov_dpp(t, 0x4E, 0xF, 0xF, true));       // quad xor2
    t = min(t, __builtin_amdgcn_mov_dpp(t, 0x141, 0xF, 0xF, true));      // half mirror
    return t;
}

__global__ __launch_bounds__(256) void persist_kernel(
    const unsigned short* __restrict__ et,      // [N_FILT][N_NODES*8]
    const unsigned short* __restrict__ pos16,   // [N_FILT][N_NODES]
    unsigned short* __restrict__ death16)       // [N_FILT][N_NODES]
{
    const int f    = blockIdx.x;
    const int tid  = threadIdx.x;
    const int lane = tid & 63;

    __shared__ unsigned int   s_pd[N_NODES];        // 32 KB packed par|dth
    __shared__ unsigned short s_r16[2][BLK][8];     // 8 KB snapshot roots (dbuf)
    __shared__ unsigned short s_list[2][3 * 96];    // per-wave ordered sublists
    __shared__ int s_wc[2][3];
    volatile unsigned int* vpd = s_pd;

    for (int v = tid; v < N_NODES; v += 256) s_pd[v] = (unsigned)v;  // par=v, dth=0
    __syncthreads();

    const unsigned short* etf = et + (size_t)f * (N_NODES * MAXDEG);

    for (int it = 0; it <= NB; ++it) {
        if (tid >= 64) {
            if (it < NB) {
                // ---- classify block `it` (waves 1-3) ----
                const int lo  = it * BLK;
                const int w   = (tid >> 6) - 1;            // 0,1,2
                const int buf = it & 1;
                const int cbase = (w == 0) ? 0 : (w == 1 ? 86 : 171);
                const int csize = (w == 0) ? 86 : 85;
                int nimp = 0;
                #pragma unroll
                for (int rnd = 0; rnd < 2; ++rnd) {
                    const int off = rnd * 64 + lane;
                    const bool active = (off < csize);
                    const int sl = cbase + off;
                    const int s  = lo + sl;
                    bool impure = false;
                    int pk[8];
                    if (active) {
                        uint4 raw = *reinterpret_cast<const uint4*>(etf + (size_t)s * 8);
                        int e8[8];
                        e8[0] = raw.x & 0xffff; e8[1] = raw.x >> 16;
                        e8[2] = raw.y & 0xffff; e8[3] = raw.y >> 16;
                        e8[4] = raw.z & 0xffff; e8[5] = raw.z >> 16;
                        e8[6] = raw.w & 0xffff; e8[7] = raw.w >> 16;
                        #pragma unroll
                        for (int k = 0; k < 8; ++k) pk[k] = e8[k];
                        // pass 1: batched chase
                        for (;;) {
                            int qk[8];
                            #pragma unroll
                            for (int k = 0; k < 8; ++k) qk[k] = (int)(vpd[pk[k]] & 0xffffu);
                            bool done = true;
                            #pragma unroll
                            for (int k = 0; k < 8; ++k) { done &= (qk[k] == pk[k]); pk[k] = qk[k]; }
                            if (done) break;
                        }
                        int first = -1; bool same = true;
                        #pragma unroll
                        for (int k = 0; k < 8; ++k) {
                            if (e8[k] == s) continue;          // invalid/self edge
                            if (first < 0) first = pk[k];
                            else same &= (pk[k] == first);
                        }
                        if (first >= 0 && same) {
                            vpd[s] = (unsigned)first | ((unsigned)s << 16);
                        } else if (first >= 0) {
                            // pass 2 (opportunistic, no barrier): re-chase
                            for (;;) {
                                int qk[8];
                                #pragma unroll
                                for (int k = 0; k < 8; ++k) qk[k] = (int)(vpd[pk[k]] & 0xffffu);
                                bool done = true;
                                #pragma unroll
                                for (int k = 0; k < 8; ++k) { done &= (qk[k] == pk[k]); pk[k] = qk[k]; }
                                if (done) break;
                            }
                            int f2 = -1; bool same2 = true;
                            #pragma unroll
                            for (int k = 0; k < 8; ++k) {
                                if (e8[k] == s) continue;
                                if (f2 < 0) f2 = pk[k];
                                else same2 &= (pk[k] == f2);
                            }
                            if (same2) vpd[s] = (unsigned)f2 | ((unsigned)s << 16);
                            else impure = true;
                        }
                    }
                    unsigned long long bal = __ballot(impure);
                    int within = __popcll(bal & ((1ull << lane) - 1ull));
                    if (impure) {
                        s_list[buf][w * 96 + nimp + within] = (unsigned short)sl;
                        #pragma unroll
                        for (int k = 0; k < 8; ++k)
                            s_r16[buf][sl][k] = (unsigned short)pk[k];
                    }
                    nimp += __popcll(bal);
                }
                if (lane == 0) s_wc[buf][w] = nimp;
            }
        } else {
            if (it > 0) {
                // ---- wave 0: exact serial replay of block it-1 ----
                const int lo  = (it - 1) * BLK;
                const int buf = (it - 1) & 1;
                for (int seg = 0; seg < 3; ++seg) {
                    const int cnt = s_wc[buf][seg];
                    if (cnt == 0) continue;
                    const unsigned short* lst = &s_list[buf][seg * 96];
                    int t_cur = (int)lst[0];
                    int p_cur = (int)s_r16[buf][t_cur][lane & 7];
                    for (int i = 0; i < cnt; ++i) {
                        int t_nxt = (int)lst[(i + 1 < cnt) ? (i + 1) : i];
                        int p_nxt = (int)s_r16[buf][t_nxt][lane & 7]; // prefetch
                        const int sv = lo + t_cur;
                        int p = p_cur;                                // ancestor start
                        for (;;) {
                            int q = (int)(vpd[p] & 0xffffu);
                            if (__all(q == p)) break;
                            p = q;
                        }
                        int m = row8min(p);                           // elder
                        if (lane < 8 && p != m)                       // kill roots
                            vpd[p] = (unsigned)m | ((unsigned)sv << 16);
                        if (lane == 0)                                // virgin dies
                            vpd[sv] = (unsigned)m | ((unsigned)sv << 16);
                        t_cur = t_nxt; p_cur = p_nxt;
                    }
                }
            }
        }
        __syncthreads();
    }

    // emit deaths by node id; 0 -> N (undying)
    for (int n = tid; n < N_NODES; n += 256) {
        int p = (int)pos16[(f << 13) + n];
        int d = (int)(s_pd[p] >> 16);
        death16[(f << 13) + n] = (unsigned short)(d ? d : N_NODES);
    }
}

// ---------------------------------------------------------------------------
// Kernel C: out[n][f] = X[n][f] + pooled[n]*Wr[f] + br[f], with wsum and
// pooled fused in:  wsum[j] = sum_h Wt[h][j], wsum[8] = sum_h bt[h];
// pooled[n] = wsum[8] + sum_f pos_f[n]*wsum[2f] + death_f[n]*wsum[2f+1]
// ---------------------------------------------------------------------------
__global__ __launch_bounds__(256) void out_kernel(
    const float* __restrict__ X, const float* __restrict__ Wr,
    const float* __restrict__ br,
    const unsigned short* __restrict__ pos16,
    const unsigned short* __restrict__ death16,
    const float* __restrict__ Wt, const float* __restrict__ bt,
    float* __restrict__ out)
{
    __shared__ float s_ws[9];
    const int node = blockIdx.x;
    if (threadIdx.x < 9) {
        float s = 0.f;
        if (threadIdx.x < 8) {
            #pragma unroll 8
            for (int hh = 0; hh < 64; ++hh) s += Wt[hh * 8 + threadIdx.x];
        } else {
            #pragma unroll 8
            for (int hh = 0; hh < 64; ++hh) s += bt[hh];
        }
        s_ws[threadIdx.x] = s;
    }
    __syncthreads();

    float pl = s_ws[8];
    #pragma unroll
    for (int i = 0; i < N_FILT; ++i) {
        pl += (float)pos16[(i << 13) + node]   * s_ws[2 * i + 0]
            + (float)death16[(i << 13) + node] * s_ws[2 * i + 1];
    }
    const int fb = threadIdx.x * 4;
    const float4 xv = *reinterpret_cast<const float4*>(X + (size_t)node * N_FEAT + fb);
    const float4 wv = *reinterpret_cast<const float4*>(Wr + fb);
    const float4 bv = *reinterpret_cast<const float4*>(br + fb);
    float4 o;
    o.x = xv.x + pl * wv.x + bv.x;
    o.y = xv.y + pl * wv.y + bv.y;
    o.z = xv.z + pl * wv.z + bv.z;
    o.w = xv.w + pl * wv.w + bv.w;
    *reinterpret_cast<float4*>(out + (size_t)node * N_FEAT + fb) = o;
}

// ---------------------------------------------------------------------------
extern "C" void kernel_launch(void* const* d_in, const int* in_sizes, int n_in,
                              void* d_out, int out_size, void* d_ws, size_t ws_size,
                              hipStream_t stream) {
    const float* X  = (const float*)d_in[0];
    const int* edge = (const int*)d_in[1];
    const float* W1 = (const float*)d_in[2];
    const float* b1 = (const float*)d_in[3];
    const float* W2 = (const float*)d_in[4];
    const float* b2 = (const float*)d_in[5];
    const float* Wt = (const float*)d_in[6];
    const float* bt = (const float*)d_in[7];
    const float* Wr = (const float*)d_in[8];
    const float* br = (const float*)d_in[9];

    const int* edge_dst = edge + N_NODES * MAXDEG;  // row 1 of edge_list

    // ws layout (bytes):
    //   [0,        131072)  filtT    f32[4][8192]
    //   [131072,   196608)  pos16    u16[4][8192]
    //   [196608,   262144)  order16  u16[4][8192]   (aliased as death16 after etable)
    //   [262144,   786432)  et       u16[4][65536]  (first half aliased as partial)
    char* wsb = (char*)d_ws;
    float*          filtT   = (float*)(wsb);
    unsigned short* pos16   = (unsigned short*)(wsb + 131072);
    unsigned short* order16 = (unsigned short*)(wsb + 196608);
    unsigned short* death16 = (unsigned short*)(wsb + 196608); // alias, later
    unsigned short* partial = (unsigned short*)(wsb + 262144); // alias with et
    unsigned short* et      = (unsigned short*)(wsb + 262144);

    hipLaunchKernelGGL(filt_kernel,  dim3(N_NODES / 8), dim3(256), 0, stream,
                       X, W1, b1, W2, b2, filtT);
    hipLaunchKernelGGL(rank_partial_kernel, dim3(512), dim3(256), 0, stream,
                       filtT, partial);
    hipLaunchKernelGGL(rank_final_kernel, dim3(128), dim3(256), 0, stream,
                       partial, pos16, order16);
    hipLaunchKernelGGL(etable_kernel, dim3(4 * 32), dim3(256), 0, stream,
                       order16, pos16, edge_dst, et);
    hipLaunchKernelGGL(persist_kernel, dim3(N_FILT), dim3(256), 0, stream,
                       et, pos16, death16);
    hipLaunchKernelGGL(out_kernel,   dim3(N_NODES), dim3(256), 0, stream,
                       X, Wr, br, pos16, death16, Wt, bt, (float*)d_out);
}

// Round 10
// 671.531 us; speedup vs baseline: 1.1132x; 1.1132x over previous
//
#include <hip/hip_runtime.h>

#define N_NODES     8192
#define N_FEAT      1024
#define N_FILT      4
#define MAXDEG      8
#define BLK         256     // steps per speculation block

// ---------------------------------------------------------------------------
// Kernel A: filtT[f][v] = (relu(X @ W1^T + b1) @ W2^T + b2)[v][f]
// ---------------------------------------------------------------------------
__global__ __launch_bounds__(256) void filt_kernel(
    const float* __restrict__ X, const float* __restrict__ W1,
    const float* __restrict__ b1, const float* __restrict__ W2,
    const float* __restrict__ b2, float* __restrict__ filtT)
{
    const int node = blockIdx.x * 8 + (threadIdx.x >> 5);
    const int h    = threadIdx.x & 31;
    const float* xr = X  + (size_t)node * N_FEAT;
    const float* wr = W1 + (size_t)h    * N_FEAT;
    float acc = 0.f;
    for (int j = 0; j < N_FEAT; j += 4) {
        float4 xv = *reinterpret_cast<const float4*>(xr + j);
        float4 wv = *reinterpret_cast<const float4*>(wr + j);
        acc += xv.x * wv.x + xv.y * wv.y + xv.z * wv.z + xv.w * wv.w;
    }
    float hv = fmaxf(acc + b1[h], 0.f);
    #pragma unroll
    for (int fo = 0; fo < N_FILT; ++fo) {
        float v = hv * W2[fo * 32 + h];
        for (int off = 16; off; off >>= 1) v += __shfl_xor(v, off, 32);
        if (h == 0) filtT[fo * N_NODES + node] = v + b2[fo];
    }
}

// ---------------------------------------------------------------------------
// Kernel W: wsum[j] = sum_h Wt[h][j] (j=0..7), wsum[8] = sum_h bt[h]
// ---------------------------------------------------------------------------
__global__ void wsum_kernel(const float* __restrict__ Wt,
                            const float* __restrict__ bt,
                            float* __restrict__ wsum)
{
    int t = threadIdx.x;
    if (t < 8) {
        float s = 0.f;
        for (int hh = 0; hh < 64; ++hh) s += Wt[hh * 8 + t];
        wsum[t] = s;
    } else if (t == 8) {
        float s = 0.f;
        for (int hh = 0; hh < 64; ++hh) s += bt[hh];
        wsum[8] = s;
    }
}

// ---------------------------------------------------------------------------
// Kernel R1: partial stable-rank. 512 blocks: f(2b) x scan-chunk cs(2b) x
// vertex-chunk cv(5b).
// ---------------------------------------------------------------------------
__global__ __launch_bounds__(256) void rank_partial_kernel(
    const float* __restrict__ filtT, unsigned short* __restrict__ partial)
{
    const int b  = blockIdx.x;
    const int f  = b >> 7;
    const int cs = (b >> 5) & 3;
    const int cv = b & 31;
    const int v  = (cv << 8) + threadIdx.x;
    const float myv = filtT[(f << 13) + v];

    __shared__ float4 tile[512];
    const float4* src = reinterpret_cast<const float4*>(filtT + (f << 13) + cs * 2048);
    for (int i = threadIdx.x; i < 512; i += 256) tile[i] = src[i];
    __syncthreads();

    int cnt = 0;
    const int ubase = cs * 2048;
    #pragma unroll 4
    for (int j = 0; j < 512; ++j) {
        float4 wv = tile[j];
        int u = ubase + j * 4;
        cnt += (wv.x < myv) || (wv.x == myv && (u + 0) < v);
        cnt += (wv.y < myv) || (wv.y == myv && (u + 1) < v);
        cnt += (wv.z < myv) || (wv.z == myv && (u + 2) < v);
        cnt += (wv.w < myv) || (wv.w == myv && (u + 3) < v);
    }
    partial[((f * 4 + cs) << 13) + v] = (unsigned short)cnt;
}

// ---------------------------------------------------------------------------
// Kernel R2: pos = sum of 4 partials; order[pos] = v.
// ---------------------------------------------------------------------------
__global__ __launch_bounds__(256) void rank_final_kernel(
    const unsigned short* __restrict__ partial,
    unsigned short* __restrict__ pos16, unsigned short* __restrict__ order16)
{
    int g = blockIdx.x * 256 + threadIdx.x;   // 0 .. 32767
    int f = g >> 13, v = g & 8191;
    int r = (int)partial[((f * 4 + 0) << 13) + v]
          + (int)partial[((f * 4 + 1) << 13) + v]
          + (int)partial[((f * 4 + 2) << 13) + v]
          + (int)partial[((f * 4 + 3) << 13) + v];
    pos16[(f << 13) + v] = (unsigned short)r;
    order16[(f << 13) + r] = (unsigned short)v;
}

// ---------------------------------------------------------------------------
// Kernel E: static edge filter.  et[f][s*8+k] = min(pos[dst[order[s]*8+k]], s)
// ---------------------------------------------------------------------------
__global__ __launch_bounds__(256) void etable_kernel(
    const unsigned short* __restrict__ order16,
    const unsigned short* __restrict__ pos16,
    const int* __restrict__ edge_dst,
    unsigned short* __restrict__ et)
{
    const int f  = blockIdx.x >> 5;
    const int e0 = ((blockIdx.x & 31) << 11);
    for (int i = threadIdx.x; i < 2048; i += 256) {
        int e = e0 + i;
        int s = e >> 3, k = e & 7;
        int v = (int)order16[(f << 13) + s];
        int u = edge_dst[v * MAXDEG + k];
        int q = (int)pos16[(f << 13) + u];
        et[(size_t)f * (N_NODES * MAXDEG) + e] = (unsigned short)(q < s ? q : s);
    }
}

// ---------------------------------------------------------------------------
// Kernel B: block-speculative union-find (R8 structure) + HELPER WAVES.
// pd[v] = par | (dth<<16); parents strictly decrease (point to older pos).
// Per 256-step block:
//   pass 1 (parallel, 1 thread/step): batched 8-way chase; pure -> attach.
//   barrier; pass 2: re-chase candidates (kills visibility false-impures).
//   compact impure list (contiguous, ascending); barrier.
//   replay phase: wave 0 exactly replays impure items, publishing a
//     volatile progress watermark; waves 1-3 continuously re-chase the
//     snapshot roots s_r16 of NOT-YET-CONSUMED items toward current roots
//     (monotone, 2-byte-atomic; replay reads old-or-new = valid ancestor),
//     keeping wave-0's find depth ~1.  Completion via monotone block token.
// Soundness: pure attach requires all edges chase to ONE vertex (their
// components at step s all contain it -> single component); ancestors
// suffice as parents; staleness only creates FALSE impures, resolved
// exactly by the ordered replay.
// ---------------------------------------------------------------------------
__device__ __forceinline__ int row8min(int v) {
    int t = min(v, __builtin_amdgcn_mov_dpp(v, 0xB1, 0xF, 0xF, true));   // quad xor1
    t = min(t, __builtin_amdgcn_mov_dpp(t, 0x4E, 0xF, 0xF, true));       // quad xor2
    t = min(t, __builtin_amdgcn_mov_dpp(t, 0x141, 0xF, 0xF, true));      // half mirror
    return t;
}

__global__ __launch_bounds__(256) void persist_kernel(
    const unsigned short* __restrict__ et,      // [N_FILT][N_NODES*8]
    const unsigned short* __restrict__ pos16,   // [N_FILT][N_NODES]
    unsigned short* __restrict__ death16)       // [N_FILT][N_NODES]
{
    const int f    = blockIdx.x;
    const int tid  = threadIdx.x;
    const int lane = tid & 63;
    const int w    = tid >> 6;

    __shared__ unsigned int   s_pd[N_NODES];        // 32 KB packed par|dth
    __shared__ unsigned short s_r16[BLK][8];        // 4 KB replay snapshot roots
    __shared__ unsigned short s_list[BLK];          // impure list (contiguous)
    __shared__ int s_wc[4];
    __shared__ int s_tok;                           // monotone block token
    __shared__ int s_prog;                          // replay watermark
    volatile unsigned int*   vpd  = s_pd;
    volatile unsigned short* vr16 = &s_r16[0][0];
    volatile int* vtok  = &s_tok;
    volatile int* vprog = &s_prog;

    for (int v = tid; v < N_NODES; v += 256) s_pd[v] = (unsigned)v;  // par=v, dth=0
    if (tid == 0) { s_tok = 0; s_prog = 0; }
    __syncthreads();

    const unsigned short* etf = et + (size_t)f * (N_NODES * MAXDEG);
    const int NB = N_NODES / BLK;

    for (int it = 0; it < NB; ++it) {
        const int lo = it * BLK;
        const int s  = lo + tid;

        // ---- pass 1: batched 8-way chase + classify ----
        uint4 raw = *reinterpret_cast<const uint4*>(etf + (size_t)s * 8);
        int e8[8];
        e8[0] = raw.x & 0xffff; e8[1] = raw.x >> 16;
        e8[2] = raw.y & 0xffff; e8[3] = raw.y >> 16;
        e8[4] = raw.z & 0xffff; e8[5] = raw.z >> 16;
        e8[6] = raw.w & 0xffff; e8[7] = raw.w >> 16;

        int pk[8];
        #pragma unroll
        for (int k = 0; k < 8; ++k) pk[k] = e8[k];
        for (;;) {
            int qk[8];
            #pragma unroll
            for (int k = 0; k < 8; ++k) qk[k] = (int)(vpd[pk[k]] & 0xffffu);
            bool done = true;
            #pragma unroll
            for (int k = 0; k < 8; ++k) { done &= (qk[k] == pk[k]); pk[k] = qk[k]; }
            if (done) break;
        }
        int first = -1; bool same = true;
        #pragma unroll
        for (int k = 0; k < 8; ++k) {
            if (e8[k] == s) continue;               // invalid/self edge
            if (first < 0) first = pk[k];
            else same &= (pk[k] == first);
        }
        bool cand = (first >= 0) && !same;          // pass-1 impure candidate
        if (first >= 0 && same)                     // pure: attach, virgin dies at s
            vpd[s] = (unsigned)first | ((unsigned)s << 16);
        if (tid == 0) *vprog = 0;                   // reset watermark for this block

        __syncthreads();                            // pure attaches now visible

        // ---- pass 2: re-chase candidates from pass-1 roots, reclassify ----
        bool impure = false;
        if (cand) {
            for (;;) {
                int qk[8];
                #pragma unroll
                for (int k = 0; k < 8; ++k) qk[k] = (int)(vpd[pk[k]] & 0xffffu);
                bool done = true;
                #pragma unroll
                for (int k = 0; k < 8; ++k) { done &= (qk[k] == pk[k]); pk[k] = qk[k]; }
                if (done) break;
            }
            int f2 = -1; bool same2 = true;
            #pragma unroll
            for (int k = 0; k < 8; ++k) {
                if (e8[k] == s) continue;
                if (f2 < 0) f2 = pk[k];
                else same2 &= (pk[k] == f2);
            }
            if (same2) {                            // false impure: pure attach now
                vpd[s] = (unsigned)f2 | ((unsigned)s << 16);
            } else {
                impure = true;
                #pragma unroll
                for (int k = 0; k < 8; ++k) s_r16[tid][k] = (unsigned short)pk[k];
            }
        }

        // ---- compact impure list (ascending s) ----
        unsigned long long bal = __ballot(impure);
        int within = __popcll(bal & ((1ull << lane) - 1ull));
        if (lane == 0) s_wc[w] = __popcll(bal);
        __syncthreads();
        int base = 0, total = 0;
        #pragma unroll
        for (int i = 0; i < 4; ++i) { int c = s_wc[i]; if (i < w) base += c; total += c; }
        if (impure) s_list[base + within] = (unsigned short)tid;
        __syncthreads();

        // ---- replay phase: wave 0 replays; waves 1-3 compress the list ----
        if (tid < 64) {
            if (total > 0) {
                int t_cur = (int)s_list[0];
                int p_cur = (int)vr16[t_cur * 8 + (lane & 7)];
                for (int i = 0; i < total; ++i) {
                    if (lane == 0) *vprog = i;                  // watermark
                    int t_nxt = (int)s_list[(i + 1 < total) ? (i + 1) : i];
                    int p_nxt = (int)vr16[t_nxt * 8 + (lane & 7)]; // prefetch
                    const int sv = lo + t_cur;
                    int p = p_cur;                              // ancestor start
                    for (;;) {
                        int q = (int)(vpd[p] & 0xffffu);
                        if (__all(q == p)) break;
                        p = q;
                    }
                    int m = row8min(p);                         // elder
                    if (lane < 8 && p != m)                     // kill roots
                        vpd[p] = (unsigned)m | ((unsigned)sv << 16);
                    if (lane == 0)                              // virgin dies
                        vpd[sv] = (unsigned)m | ((unsigned)sv << 16);
                    t_cur = t_nxt; p_cur = p_nxt;
                }
            }
            if (lane == 0) *vtok = it + 1;                      // block done
        } else {
            // helpers: re-chase snapshot roots of unconsumed items
            const int hw = w - 1;                               // 0..2
            const int il = lane >> 3;                           // item sub-lane
            const int sl = lane & 7;                            // slot
            while (*vtok < it + 1) {
                int start = *vprog;
                for (int i = start + hw * 8 + il; i < total; i += 24) {
                    int t = (int)s_list[i];
                    int r = (int)vr16[t * 8 + sl];
                    int q = (int)(vpd[r] & 0xffffu);
                    if (q != r) vr16[t * 8 + sl] = (unsigned short)q;
                }
                __builtin_amdgcn_s_sleep(1);
            }
        }
        __syncthreads();
    }

    // emit deaths by node id; 0 -> N (undying)
    for (int n = tid; n < N_NODES; n += 256) {
        int p = (int)pos16[(f << 13) + n];
        int d = (int)(s_pd[p] >> 16);
        death16[(f << 13) + n] = (unsigned short)(d ? d : N_NODES);
    }
}

// ---------------------------------------------------------------------------
// Kernel C: out[n][f] = X[n][f] + pooled[n]*Wr[f] + br[f], pooled fused:
// pooled[n] = wsum[8] + sum_f pos_f[n]*wsum[2f] + death_f[n]*wsum[2f+1]
// ---------------------------------------------------------------------------
__global__ __launch_bounds__(256) void out_kernel(
    const float* __restrict__ X, const float* __restrict__ Wr,
    const float* __restrict__ br,
    const unsigned short* __restrict__ pos16,
    const unsigned short* __restrict__ death16,
    const float* __restrict__ wsum,
    float* __restrict__ out)
{
    const int node = blockIdx.x;
    float pl = wsum[8];
    #pragma unroll
    for (int i = 0; i < N_FILT; ++i) {
        pl += (float)pos16[(i << 13) + node]   * wsum[2 * i + 0]
            + (float)death16[(i << 13) + node] * wsum[2 * i + 1];
    }
    const int fb = threadIdx.x * 4;
    const float4 xv = *reinterpret_cast<const float4*>(X + (size_t)node * N_FEAT + fb);
    const float4 wv = *reinterpret_cast<const float4*>(Wr + fb);
    const float4 bv = *reinterpret_cast<const float4*>(br + fb);
    float4 o;
    o.x = xv.x + pl * wv.x + bv.x;
    o.y = xv.y + pl * wv.y + bv.y;
    o.z = xv.z + pl * wv.z + bv.z;
    o.w = xv.w + pl * wv.w + bv.w;
    *reinterpret_cast<float4*>(out + (size_t)node * N_FEAT + fb) = o;
}

// ---------------------------------------------------------------------------
extern "C" void kernel_launch(void* const* d_in, const int* in_sizes, int n_in,
                              void* d_out, int out_size, void* d_ws, size_t ws_size,
                              hipStream_t stream) {
    const float* X  = (const float*)d_in[0];
    const int* edge = (const int*)d_in[1];
    const float* W1 = (const float*)d_in[2];
    const float* b1 = (const float*)d_in[3];
    const float* W2 = (const float*)d_in[4];
    const float* b2 = (const float*)d_in[5];
    const float* Wt = (const float*)d_in[6];
    const float* bt = (const float*)d_in[7];
    const float* Wr = (const float*)d_in[8];
    const float* br = (const float*)d_in[9];

    const int* edge_dst = edge + N_NODES * MAXDEG;  // row 1 of edge_list

    // ws layout (bytes):
    //   [0,        131072)  filtT    f32[4][8192]
    //   [131072,   196608)  pos16    u16[4][8192]
    //   [196608,   262144)  order16  u16[4][8192]   (aliased as death16 after etable)
    //   [262144,   786432)  et       u16[4][65536]  (first half aliased as partial)
    //   [786432,   786496)  wsum     f32[16]
    char* wsb = (char*)d_ws;
    float*          filtT   = (float*)(wsb);
    unsigned short* pos16   = (unsigned short*)(wsb + 131072);
    unsigned short* order16 = (unsigned short*)(wsb + 196608);
    unsigned short* death16 = (unsigned short*)(wsb + 196608); // alias, later
    unsigned short* partial = (unsigned short*)(wsb + 262144); // alias with et
    unsigned short* et      = (unsigned short*)(wsb + 262144);
    float*          wsum    = (float*)(wsb + 786432);

    hipLaunchKernelGGL(filt_kernel,  dim3(N_NODES / 8), dim3(256), 0, stream,
                       X, W1, b1, W2, b2, filtT);
    hipLaunchKernelGGL(wsum_kernel,  dim3(1), dim3(64), 0, stream, Wt, bt, wsum);
    hipLaunchKernelGGL(rank_partial_kernel, dim3(512), dim3(256), 0, stream,
                       filtT, partial);
    hipLaunchKernelGGL(rank_final_kernel, dim3(128), dim3(256), 0, stream,
                       partial, pos16, order16);
    hipLaunchKernelGGL(etable_kernel, dim3(4 * 32), dim3(256), 0, stream,
                       order16, pos16, edge_dst, et);
    hipLaunchKernelGGL(persist_kernel, dim3(N_FILT), dim3(256), 0, stream,
                       et, pos16, death16);
    hipLaunchKernelGGL(out_kernel,   dim3(N_NODES), dim3(256), 0, stream,
                       X, Wr, br, pos16, death16, wsum, (float*)d_out);
}

// Round 11
// 646.252 us; speedup vs baseline: 1.1567x; 1.0391x over previous
//
#include <hip/hip_runtime.h>

#define N_NODES     8192
#define N_FEAT      1024
#define N_FILT      4
#define MAXDEG      8
#define BLK         256     // steps per speculation block
#define NB          (N_NODES / BLK)

// ---------------------------------------------------------------------------
// Kernel A: filtT[f][v] = (relu(X @ W1^T + b1) @ W2^T + b2)[v][f]
// ---------------------------------------------------------------------------
__global__ __launch_bounds__(256) void filt_kernel(
    const float* __restrict__ X, const float* __restrict__ W1,
    const float* __restrict__ b1, const float* __restrict__ W2,
    const float* __restrict__ b2, float* __restrict__ filtT)
{
    const int node = blockIdx.x * 8 + (threadIdx.x >> 5);
    const int h    = threadIdx.x & 31;
    const float* xr = X  + (size_t)node * N_FEAT;
    const float* wr = W1 + (size_t)h    * N_FEAT;
    float acc = 0.f;
    for (int j = 0; j < N_FEAT; j += 4) {
        float4 xv = *reinterpret_cast<const float4*>(xr + j);
        float4 wv = *reinterpret_cast<const float4*>(wr + j);
        acc += xv.x * wv.x + xv.y * wv.y + xv.z * wv.z + xv.w * wv.w;
    }
    float hv = fmaxf(acc + b1[h], 0.f);
    #pragma unroll
    for (int fo = 0; fo < N_FILT; ++fo) {
        float v = hv * W2[fo * 32 + h];
        for (int off = 16; off; off >>= 1) v += __shfl_xor(v, off, 32);
        if (h == 0) filtT[fo * N_NODES + node] = v + b2[fo];
    }
}

// ---------------------------------------------------------------------------
// Kernel W: wsum[j] = sum_h Wt[h][j] (j=0..7), wsum[8] = sum_h bt[h]
// ---------------------------------------------------------------------------
__global__ void wsum_kernel(const float* __restrict__ Wt,
                            const float* __restrict__ bt,
                            float* __restrict__ wsum)
{
    int t = threadIdx.x;
    if (t < 8) {
        float s = 0.f;
        for (int hh = 0; hh < 64; ++hh) s += Wt[hh * 8 + t];
        wsum[t] = s;
    } else if (t == 8) {
        float s = 0.f;
        for (int hh = 0; hh < 64; ++hh) s += bt[hh];
        wsum[8] = s;
    }
}

// ---------------------------------------------------------------------------
// Kernel R1: partial stable-rank. 512 blocks: f(2b) x scan-chunk cs(2b) x
// vertex-chunk cv(5b).
// ---------------------------------------------------------------------------
__global__ __launch_bounds__(256) void rank_partial_kernel(
    const float* __restrict__ filtT, unsigned short* __restrict__ partial)
{
    const int b  = blockIdx.x;
    const int f  = b >> 7;
    const int cs = (b >> 5) & 3;
    const int cv = b & 31;
    const int v  = (cv << 8) + threadIdx.x;
    const float myv = filtT[(f << 13) + v];

    __shared__ float4 tile[512];
    const float4* src = reinterpret_cast<const float4*>(filtT + (f << 13) + cs * 2048);
    for (int i = threadIdx.x; i < 512; i += 256) tile[i] = src[i];
    __syncthreads();

    int cnt = 0;
    const int ubase = cs * 2048;
    #pragma unroll 4
    for (int j = 0; j < 512; ++j) {
        float4 wv = tile[j];
        int u = ubase + j * 4;
        cnt += (wv.x < myv) || (wv.x == myv && (u + 0) < v);
        cnt += (wv.y < myv) || (wv.y == myv && (u + 1) < v);
        cnt += (wv.z < myv) || (wv.z == myv && (u + 2) < v);
        cnt += (wv.w < myv) || (wv.w == myv && (u + 3) < v);
    }
    partial[((f * 4 + cs) << 13) + v] = (unsigned short)cnt;
}

// ---------------------------------------------------------------------------
// Kernel R2: pos = sum of 4 partials; order[pos] = v.
// ---------------------------------------------------------------------------
__global__ __launch_bounds__(256) void rank_final_kernel(
    const unsigned short* __restrict__ partial,
    unsigned short* __restrict__ pos16, unsigned short* __restrict__ order16)
{
    int g = blockIdx.x * 256 + threadIdx.x;   // 0 .. 32767
    int f = g >> 13, v = g & 8191;
    int r = (int)partial[((f * 4 + 0) << 13) + v]
          + (int)partial[((f * 4 + 1) << 13) + v]
          + (int)partial[((f * 4 + 2) << 13) + v]
          + (int)partial[((f * 4 + 3) << 13) + v];
    pos16[(f << 13) + v] = (unsigned short)r;
    order16[(f << 13) + r] = (unsigned short)v;
}

// ---------------------------------------------------------------------------
// Kernel E: static edge filter.  et[f][s*8+k] = min(pos[dst[order[s]*8+k]], s)
// ---------------------------------------------------------------------------
__global__ __launch_bounds__(256) void etable_kernel(
    const unsigned short* __restrict__ order16,
    const unsigned short* __restrict__ pos16,
    const int* __restrict__ edge_dst,
    unsigned short* __restrict__ et)
{
    const int f  = blockIdx.x >> 5;
    const int e0 = ((blockIdx.x & 31) << 11);
    for (int i = threadIdx.x; i < 2048; i += 256) {
        int e = e0 + i;
        int s = e >> 3, k = e & 7;
        int v = (int)order16[(f << 13) + s];
        int u = edge_dst[v * MAXDEG + k];
        int q = (int)pos16[(f << 13) + u];
        et[(size_t)f * (N_NODES * MAXDEG) + e] = (unsigned short)(q < s ? q : s);
    }
}

// ---------------------------------------------------------------------------
// Kernel B: block-speculative union-find, pass1 PIPELINED under replay.
// pd[v] = par | (dth<<16); parents strictly decrease (point to older pos).
// Per iteration it:
//   concurrent: wave 0 exactly replays block it-1's impure list
//               waves 1-3 run pass 1 of block it (chase, pure-attach,
//               candidates -> s_r16/flag); staleness only ADDS candidates.
//   barrier
//   pass 2 (all waves, candidates only): re-chase vs fully-updated state
//     (replay(it-1) + pass-1 attaches all visible = R8 semantics);
//     newly-pure -> attach; impure -> VIRGIN-COMMIT pd[s]=min|s<<16
//     (sound: min(roots) < s is in s's final component) + updated roots.
//   barrier; list compaction (ascending); barrier.
// Soundness: every pd write stores an ancestor; chases are monotone
// decreasing; u32 reads are old-or-new (both valid ancestors); pure attach
// from a state-subset of true components is exact; false impures are
// resolved exactly by the ordered replay (they kill nothing).
// ---------------------------------------------------------------------------
__device__ __forceinline__ int row8min(int v) {
    int t = min(v, __builtin_amdgcn_mov_dpp(v, 0xB1, 0xF, 0xF, true));   // quad xor1
    t = min(t, __builtin_amdgcn_mov_dpp(t, 0x4E, 0xF, 0xF, true));       // quad xor2
    t = min(t, __builtin_amdgcn_mov_dpp(t, 0x141, 0xF, 0xF, true));      // half mirror
    return t;
}

__device__ __forceinline__ void chase8(volatile unsigned int* vpd, int (&pk)[8]) {
    for (;;) {
        int qk[8];
        #pragma unroll
        for (int k = 0; k < 8; ++k) qk[k] = (int)(vpd[pk[k]] & 0xffffu);
        bool done = true;
        #pragma unroll
        for (int k = 0; k < 8; ++k) { done &= (qk[k] == pk[k]); pk[k] = qk[k]; }
        if (done) break;
    }
}

__global__ __launch_bounds__(256) void persist_kernel(
    const unsigned short* __restrict__ et,      // [N_FILT][N_NODES*8]
    const unsigned short* __restrict__ pos16,   // [N_FILT][N_NODES]
    unsigned short* __restrict__ death16)       // [N_FILT][N_NODES]
{
    const int f    = blockIdx.x;
    const int tid  = threadIdx.x;
    const int lane = tid & 63;
    const int w    = tid >> 6;

    __shared__ unsigned int   s_pd[N_NODES];        // 32 KB packed par|dth
    __shared__ unsigned short s_r16[2][BLK][8];     // 8 KB candidate roots (dbuf)
    __shared__ unsigned char  s_flag[2][BLK];       // 0=done, 2=candidate
    __shared__ unsigned short s_list[2][BLK];       // impure list (dbuf)
    __shared__ int s_wc[2][4];
    volatile unsigned int* vpd = s_pd;

    for (int v = tid; v < N_NODES; v += 256) s_pd[v] = (unsigned)v;  // par=v, dth=0
    __syncthreads();

    const unsigned short* etf = et + (size_t)f * (N_NODES * MAXDEG);

    for (int it = 0; it <= NB; ++it) {
        const int buf = it & 1;

        // ================= concurrent phase =================
        if (w == 0) {
            if (it > 0) {
                // ---- wave 0: exact replay of block it-1 ----
                const int pbuf = (it - 1) & 1;
                const int plo  = (it - 1) * BLK;
                const int total = s_wc[pbuf][0] + s_wc[pbuf][1]
                                + s_wc[pbuf][2] + s_wc[pbuf][3];
                if (total > 0) {
                    int t_cur = (int)s_list[pbuf][0];
                    int p_cur = (int)s_r16[pbuf][t_cur][lane & 7];
                    for (int i = 0; i < total; ++i) {
                        int nidx  = (i + 1 < total) ? (i + 1) : i;
                        int t_nxt = (int)s_list[pbuf][nidx];
                        int p_nxt = (int)s_r16[pbuf][t_nxt][lane & 7]; // prefetch
                        const int sv = plo + t_cur;
                        int p = p_cur;                          // ancestor start
                        for (;;) {
                            int q = (int)(vpd[p] & 0xffffu);
                            if (__all(q == p)) break;
                            p = q;
                        }
                        int m = row8min(p);                     // elder
                        if (lane < 8 && p != m)                 // kill non-elder roots
                            vpd[p] = (unsigned)m | ((unsigned)sv << 16);
                        t_cur = t_nxt; p_cur = p_nxt;
                    }
                }
            }
        } else if (it < NB) {
            // ---- waves 1-3: pass 1 of block it ----
            const int lo = it * BLK;
            const int h  = tid - 64;                 // 0..191
            #pragma unroll
            for (int rep = 0; rep < 2; ++rep) {
                const int sl = (rep == 0) ? h : (192 + h);
                if (rep == 1 && h >= 64) break;
                const int s = lo + sl;
                uint4 raw = *reinterpret_cast<const uint4*>(etf + (size_t)s * 8);
                int e8[8];
                e8[0] = raw.x & 0xffff; e8[1] = raw.x >> 16;
                e8[2] = raw.y & 0xffff; e8[3] = raw.y >> 16;
                e8[4] = raw.z & 0xffff; e8[5] = raw.z >> 16;
                e8[6] = raw.w & 0xffff; e8[7] = raw.w >> 16;
                int pk[8];
                #pragma unroll
                for (int k = 0; k < 8; ++k) pk[k] = e8[k];
                chase8(vpd, pk);
                int first = -1; bool same = true;
                #pragma unroll
                for (int k = 0; k < 8; ++k) {
                    if (e8[k] == s) continue;        // invalid/self edge
                    if (first < 0) first = pk[k];
                    else same &= (pk[k] == first);
                }
                if (first < 0) {
                    s_flag[buf][sl] = 0;             // isolated
                } else if (same) {
                    vpd[s] = (unsigned)first | ((unsigned)s << 16);  // pure attach
                    s_flag[buf][sl] = 0;
                } else {
                    s_flag[buf][sl] = 2;             // candidate
                    #pragma unroll
                    for (int k = 0; k < 8; ++k)
                        s_r16[buf][sl][k] = (unsigned short)pk[k];
                }
            }
        }
        __syncthreads();

        // ================= pass 2 + compaction =================
        bool impure = false;
        int  within = 0;
        if (it < NB) {
            const int sl = tid;
            const int s  = it * BLK + sl;
            if (s_flag[buf][sl] == 2) {
                int pk[8];
                #pragma unroll
                for (int k = 0; k < 8; ++k) pk[k] = (int)s_r16[buf][sl][k];
                chase8(vpd, pk);                     // vs fully-updated state
                int first = -1; bool same = true; int m = pk[0];
                #pragma unroll
                for (int k = 0; k < 8; ++k) {
                    m = min(m, pk[k]);               // self slots (==s) never min
                    if (pk[k] == s) continue;        // invalid/self
                    if (first < 0) first = pk[k];
                    else same &= (pk[k] == first);
                }
                if (same) {                          // false impure -> pure attach
                    vpd[s] = (unsigned)first | ((unsigned)s << 16);
                } else {
                    impure = true;
                    #pragma unroll
                    for (int k = 0; k < 8; ++k)
                        s_r16[buf][sl][k] = (unsigned short)pk[k];
                    vpd[s] = (unsigned)m | ((unsigned)s << 16);   // virgin-commit
                }
            }
        }
        unsigned long long bal = __ballot(impure);
        within = __popcll(bal & ((1ull << lane) - 1ull));
        if (it < NB && lane == 0) s_wc[buf][w] = __popcll(bal);
        __syncthreads();
        if (it < NB && impure) {
            int base = 0;
            #pragma unroll
            for (int i = 0; i < 4; ++i) { if (i < w) base += s_wc[buf][i]; }
            s_list[buf][base + within] = (unsigned short)tid;
        }
        __syncthreads();
    }

    // emit deaths by node id; 0 -> N (undying)
    for (int n = tid; n < N_NODES; n += 256) {
        int p = (int)pos16[(f << 13) + n];
        int d = (int)(s_pd[p] >> 16);
        death16[(f << 13) + n] = (unsigned short)(d ? d : N_NODES);
    }
}

// ---------------------------------------------------------------------------
// Kernel C: out[n][f] = X[n][f] + pooled[n]*Wr[f] + br[f], pooled fused:
// pooled[n] = wsum[8] + sum_f pos_f[n]*wsum[2f] + death_f[n]*wsum[2f+1]
// ---------------------------------------------------------------------------
__global__ __launch_bounds__(256) void out_kernel(
    const float* __restrict__ X, const float* __restrict__ Wr,
    const float* __restrict__ br,
    const unsigned short* __restrict__ pos16,
    const unsigned short* __restrict__ death16,
    const float* __restrict__ wsum,
    float* __restrict__ out)
{
    const int node = blockIdx.x;
    float pl = wsum[8];
    #pragma unroll
    for (int i = 0; i < N_FILT; ++i) {
        pl += (float)pos16[(i << 13) + node]   * wsum[2 * i + 0]
            + (float)death16[(i << 13) + node] * wsum[2 * i + 1];
    }
    const int fb = threadIdx.x * 4;
    const float4 xv = *reinterpret_cast<const float4*>(X + (size_t)node * N_FEAT + fb);
    const float4 wv = *reinterpret_cast<const float4*>(Wr + fb);
    const float4 bv = *reinterpret_cast<const float4*>(br + fb);
    float4 o;
    o.x = xv.x + pl * wv.x + bv.x;
    o.y = xv.y + pl * wv.y + bv.y;
    o.z = xv.z + pl * wv.z + bv.z;
    o.w = xv.w + pl * wv.w + bv.w;
    *reinterpret_cast<float4*>(out + (size_t)node * N_FEAT + fb) = o;
}

// ---------------------------------------------------------------------------
extern "C" void kernel_launch(void* const* d_in, const int* in_sizes, int n_in,
                              void* d_out, int out_size, void* d_ws, size_t ws_size,
                              hipStream_t stream) {
    const float* X  = (const float*)d_in[0];
    const int* edge = (const int*)d_in[1];
    const float* W1 = (const float*)d_in[2];
    const float* b1 = (const float*)d_in[3];
    const float* W2 = (const float*)d_in[4];
    const float* b2 = (const float*)d_in[5];
    const float* Wt = (const float*)d_in[6];
    const float* bt = (const float*)d_in[7];
    const float* Wr = (const float*)d_in[8];
    const float* br = (const float*)d_in[9];

    const int* edge_dst = edge + N_NODES * MAXDEG;  // row 1 of edge_list

    // ws layout (bytes):
    //   [0,        131072)  filtT    f32[4][8192]
    //   [131072,   196608)  pos16    u16[4][8192]
    //   [196608,   262144)  order16  u16[4][8192]   (aliased as death16 after etable)
    //   [262144,   786432)  et       u16[4][65536]  (first half aliased as partial)
    //   [786432,   786496)  wsum     f32[16]
    char* wsb = (char*)d_ws;
    float*          filtT   = (float*)(wsb);
    unsigned short* pos16   = (unsigned short*)(wsb + 131072);
    unsigned short* order16 = (unsigned short*)(wsb + 196608);
    unsigned short* death16 = (unsigned short*)(wsb + 196608); // alias, later
    unsigned short* partial = (unsigned short*)(wsb + 262144); // alias with et
    unsigned short* et      = (unsigned short*)(wsb + 262144);
    float*          wsum    = (float*)(wsb + 786432);

    hipLaunchKernelGGL(filt_kernel,  dim3(N_NODES / 8), dim3(256), 0, stream,
                       X, W1, b1, W2, b2, filtT);
    hipLaunchKernelGGL(wsum_kernel,  dim3(1), dim3(64), 0, stream, Wt, bt, wsum);
    hipLaunchKernelGGL(rank_partial_kernel, dim3(512), dim3(256), 0, stream,
                       filtT, partial);
    hipLaunchKernelGGL(rank_final_kernel, dim3(128), dim3(256), 0, stream,
                       partial, pos16, order16);
    hipLaunchKernelGGL(etable_kernel, dim3(4 * 32), dim3(256), 0, stream,
                       order16, pos16, edge_dst, et);
    hipLaunchKernelGGL(persist_kernel, dim3(N_FILT), dim3(256), 0, stream,
                       et, pos16, death16);
    hipLaunchKernelGGL(out_kernel,   dim3(N_NODES), dim3(256), 0, stream,
                       X, Wr, br, pos16, death16, wsum, (float*)d_out);
}